// Round 10
// baseline (478.949 us; speedup 1.0000x reference)
//
#include <hip/hip_runtime.h>
#include <hip/hip_bf16.h>

typedef __attribute__((ext_vector_type(8))) short bf16x8;
typedef __attribute__((ext_vector_type(4))) float f32x4;

#define MFMA(a,b,c) __builtin_amdgcn_mfma_f32_16x16x32_bf16((a),(b),(c),0,0,0)
#define WAVE_LDS_FENCE() do { asm volatile("s_waitcnt lgkmcnt(0)" ::: "memory"); \
                              __builtin_amdgcn_sched_barrier(0); } while (0)

static constexpr int NTOK = 8 * 8 * 56 * 56;   // 200704 tokens
static constexpr int NT   = 98;                // tokens per window
static constexpr int NWIN = 2048;              // total windows
static constexpr int NN   = NT * NT;           // 9604

__device__ __forceinline__ unsigned short f2bf(float f) {
  unsigned r;
  asm("v_cvt_pk_bf16_f32 %0, %1, %1" : "=v"(r) : "v"(f));
  return (unsigned short)r;
}
__device__ __forceinline__ unsigned f2bf2(float lo, float hi) {
  unsigned r;
  asm("v_cvt_pk_bf16_f32 %0, %1, %2" : "=v"(r) : "v"(lo), "v"(hi));
  return r;
}
__device__ __forceinline__ float bf2f(unsigned short s) {
  union { unsigned u; float f; } v; v.u = ((unsigned)s) << 16; return v.f;
}
union U8 { unsigned u[4]; bf16x8 v; };

// map window-token t -> spatial row index (shifted partition)
__device__ __forceinline__ size_t srow_of(int t) {
  int widx = t / NT, n = t - widx * NT;
  int bb = widx >> 8, wb = widx & 255;
  int dW = wb >> 6, hW = (wb >> 3) & 7, wW = wb & 7;
  int dr = n / 49, rem = n - dr * 49, hr = rem / 7, wr = rem - hr * 7;
  int dsh = (dW * 2 + dr + 1) & 7;
  int hs = hW * 7 + hr + 3; if (hs >= 56) hs -= 56;
  int wsv = wW * 7 + wr + 3; if (wsv >= 56) wsv -= 56;
  return ((size_t)(bb * 8 + dsh) * 56 + hs) * 56 + wsv;
}

// ---------------- K0: weight transpose + bf16 cast + LN1/scale fold --------
__global__ __launch_bounds__(256) void k0_prep(
    const float* __restrict__ qkv_w, const float* __restrict__ proj_w,
    const float* __restrict__ fc1_w, const float* __restrict__ fc2_w,
    const float* __restrict__ n1g, const float* __restrict__ n1b,
    const float* __restrict__ qkv_b,
    unsigned short* __restrict__ qkvT, unsigned short* __restrict__ projT,
    unsigned short* __restrict__ fc1T, unsigned short* __restrict__ fc2T,
    float* __restrict__ qbb) {
  int idx = blockIdx.x * 256 + threadIdx.x;
  if (idx < 384 * 128) {
    int n = idx >> 7, k = idx & 127;
    float sc = n < 128 ? 0.17677669529663687f : 1.0f;
    qkvT[idx] = f2bf(qkv_w[k * 384 + n] * n1g[k] * sc);
  }
  if (idx < 128 * 128) { int n = idx >> 7, k = idx & 127; projT[idx] = f2bf(proj_w[k * 128 + n]); }
  if (idx < 512 * 128) { int n = idx >> 7, k = idx & 127; fc1T[idx] = f2bf(fc1_w[k * 512 + n]); }
  if (idx < 128 * 512) { int n = idx >> 9, k = idx & 511; fc2T[idx] = f2bf(fc2_w[k * 128 + n]); }
  if (idx < 384) {
    float acc = qkv_b[idx];
    for (int k = 0; k < 128; ++k) acc += n1b[k] * qkv_w[k * 384 + idx];
    qbb[idx] = acc * (idx < 128 ? 0.17677669529663687f : 1.0f);
  }
}

// ---------------- K0b: combined bias+mask table, 8 mask classes ------------
__global__ __launch_bounds__(256) void k0b_cmb(
    const int* __restrict__ rel, const float* __restrict__ rpb,
    const float* __restrict__ mask, unsigned short* __restrict__ cmb) {
  int idx = blockIdx.x * 256 + threadIdx.x;
  if (idx >= 4 * 8 * NN) return;
  int h = idx / (8 * NN);
  int rem = idx - h * 8 * NN;
  int cls = rem / NN, r = rem - cls * NN;
  int wb_rep = ((cls >> 2) & 1 ? 192 : 0) + ((cls >> 1) & 1 ? 56 : 0) + ((cls & 1) ? 7 : 0);
  cmb[idx] = f2bf(rpb[rel[r] * 4 + h] + mask[(size_t)wb_rep * NN + r]);
}

// ---------------- K2: fused LN1 + shift/partition + QKV GEMM ---------------
__global__ __launch_bounds__(256, 2) void k2_qkv(
    const float* __restrict__ x, const unsigned short* __restrict__ qkvT,
    const float* __restrict__ qbb,
    unsigned short* __restrict__ q, unsigned short* __restrict__ k,
    unsigned short* __restrict__ v) {
  __shared__ __align__(16) unsigned short wsW[64 * 136];   // 17408 B
  int tid = threadIdx.x, wv = tid >> 6, lane = tid & 63;
  int l15 = lane & 15, lhi = lane >> 4;
  int mbase = blockIdx.x * 128 + wv * 32;

  bf16x8 afr[2][4];
#pragma unroll
  for (int mt = 0; mt < 2; ++mt) {
    int row = mbase + mt * 16 + l15;
    size_t srow = srow_of(row);
    const float* xr = x + srow * 128 + lhi * 8;
    float xv[4][8];
    float s = 0.f, ss = 0.f;
#pragma unroll
    for (int ks = 0; ks < 4; ++ks) {
      float4 lo = *(const float4*)(xr + ks * 32);
      float4 hi = *(const float4*)(xr + ks * 32 + 4);
      xv[ks][0] = lo.x; xv[ks][1] = lo.y; xv[ks][2] = lo.z; xv[ks][3] = lo.w;
      xv[ks][4] = hi.x; xv[ks][5] = hi.y; xv[ks][6] = hi.z; xv[ks][7] = hi.w;
#pragma unroll
      for (int e = 0; e < 8; ++e) { s += xv[ks][e]; ss += xv[ks][e] * xv[ks][e]; }
    }
    s += __shfl_xor(s, 16);  ss += __shfl_xor(ss, 16);
    s += __shfl_xor(s, 32);  ss += __shfl_xor(ss, 32);
    float mu = s * (1.f / 128.f);
    float var = ss * (1.f / 128.f) - mu * mu;
    float inv = __builtin_amdgcn_rsqf(var + 1e-5f);
#pragma unroll
    for (int ks = 0; ks < 4; ++ks) {
      U8 t;
#pragma unroll
      for (int p = 0; p < 4; ++p)
        t.u[p] = f2bf2((xv[ks][2 * p] - mu) * inv, (xv[ks][2 * p + 1] - mu) * inv);
      afr[mt][ks] = t.v;
    }
  }

  int rbase[2][4];
#pragma unroll
  for (int mt = 0; mt < 2; ++mt)
#pragma unroll
    for (int j = 0; j < 4; ++j) {
      int r = mbase + mt * 16 + lhi * 4 + j;
      int widx = r / NT, n = r - widx * NT;
      rbase[mt][j] = widx * 392 + n;
    }

  bf16x8 pf[4];
#pragma unroll
  for (int u = 0; u < 4; ++u) pf[u] = *(const bf16x8*)(qkvT + u * 2048 + tid * 8);

  for (int ch = 0; ch < 6; ++ch) {
#pragma unroll
    for (int u = 0; u < 4; ++u) {
      int flat = u * 2048 + tid * 8;
      *(bf16x8*)(&wsW[(flat >> 7) * 136 + (flat & 127)]) = pf[u];
    }
    __syncthreads();
    if (ch < 5) {
#pragma unroll
      for (int u = 0; u < 4; ++u)
        pf[u] = *(const bf16x8*)(qkvT + (ch + 1) * 8192 + u * 2048 + tid * 8);
    }
    f32x4 acc[2][4] = {};
#pragma unroll
    for (int ks = 0; ks < 4; ++ks)
#pragma unroll
      for (int nt = 0; nt < 4; ++nt) {
        bf16x8 bfr = *(const bf16x8*)(&wsW[(nt * 16 + l15) * 136 + ks * 32 + lhi * 8]);
#pragma unroll
        for (int mt = 0; mt < 2; ++mt)
          acc[mt][nt] = MFMA(afr[mt][ks], bfr, acc[mt][nt]);
      }
#pragma unroll
    for (int nt = 0; nt < 4; ++nt) {
      int col = ch * 64 + nt * 16 + l15;
      int which = col >> 7, head = (col >> 5) & 3, hd = col & 31;
      unsigned short* outb = which == 0 ? q : (which == 1 ? k : v);
      float bias = qbb[col];
#pragma unroll
      for (int mt = 0; mt < 2; ++mt)
#pragma unroll
        for (int j = 0; j < 4; ++j) {
          float val = acc[mt][nt][j] + bias;
          outb[(size_t)(rbase[mt][j] + head * 98) * 32 + hd] = f2bf(val);
        }
    }
    __syncthreads();
  }
}

// ---------------- K3: window attention, 512 thr, one 16-row tile per wave --
__global__ __launch_bounds__(512) void k3_attn(
    const unsigned short* __restrict__ q, const unsigned short* __restrict__ kk,
    const unsigned short* __restrict__ vv, const unsigned short* __restrict__ cmb,
    unsigned short* __restrict__ out) {
  __shared__ __align__(16) unsigned short Vt[32 * 140];    // 8960 B
  __shared__ __align__(16) unsigned short Pw[7][16 * 140]; // 31360 B
  int bid = blockIdx.x;
  int widx = bid >> 2, head = bid & 3;
  int wb = widx & 255;
  size_t base = (size_t)(widx * 4 + head) * NT * 32;
  int tid = threadIdx.x, wv = tid >> 6, lane = tid & 63;
  int l15 = lane & 15, lhi = lane >> 4;

  for (int idx = tid; idx < NT * 32; idx += 512) {
    int j = idx >> 5, d = idx & 31;
    Vt[d * 140 + j] = vv[base + idx];
  }
  for (int idx = tid; idx < 32 * 30; idx += 512) {
    int d = idx / 30, j = 98 + idx % 30;
    Vt[d * 140 + j] = 0;
  }
  __syncthreads();
  if (wv >= 7) return;           // no barriers after this point

  int cls = (((wb >> 6) == 3) << 2) | ((((wb >> 3) & 7) == 7) << 1) | ((int)((wb & 7) == 7));
  const unsigned short* cw = cmb + ((size_t)(head * 8 + cls)) * NN;
  unsigned short* P = Pw[wv];
  int mb = wv * 16;

  bf16x8 afr = *(const bf16x8*)(q + base + (size_t)(mb + l15) * 32 + lhi * 8);
  f32x4 sfr[7];
#pragma unroll
  for (int nt = 0; nt < 7; ++nt) {
    bf16x8 bfr = *(const bf16x8*)(kk + base + (size_t)(nt * 16 + l15) * 32 + lhi * 8);
    f32x4 zz = {};
    sfr[nt] = MFMA(afr, bfr, zz);
  }
#pragma unroll
  for (int j = 0; j < 4; ++j) {
    int i = mb + lhi * 4 + j;
    int ic = i < 97 ? i : 97;
    float sv[7];
#pragma unroll
    for (int nt = 0; nt < 7; ++nt) {
      int colc = nt * 16 + l15;
      int jc = colc < 97 ? colc : 97;
      float s = fminf(fmaxf(sfr[nt][j], -1e4f), 1e4f);
      float bm = bf2f(cw[ic * NT + jc]);
      sv[nt] = (i < NT && colc < NT) ? (s + bm) : -1e30f;
    }
    float mx = sv[0];
#pragma unroll
    for (int nt = 1; nt < 7; ++nt) mx = fmaxf(mx, sv[nt]);
#pragma unroll
    for (int m2 = 1; m2 < 16; m2 <<= 1) mx = fmaxf(mx, __shfl_xor(mx, m2));
    float sum = 0.f, p[7];
#pragma unroll
    for (int nt = 0; nt < 7; ++nt) { p[nt] = __expf(sv[nt] - mx); sum += p[nt]; }
#pragma unroll
    for (int m2 = 1; m2 < 16; m2 <<= 1) sum += __shfl_xor(sum, m2);
    float inv = __builtin_amdgcn_rcpf(sum);
    int iloc = lhi * 4 + j;
#pragma unroll
    for (int nt = 0; nt < 7; ++nt)
      P[iloc * 140 + nt * 16 + l15] = f2bf(p[nt] * inv);
    P[iloc * 140 + 112 + l15] = 0;
  }
  WAVE_LDS_FENCE();

  f32x4 ofr[2] = {};
#pragma unroll
  for (int ks = 0; ks < 4; ++ks) {
    bf16x8 pafr = *(const bf16x8*)(P + l15 * 140 + ks * 32 + lhi * 8);
#pragma unroll
    for (int nt = 0; nt < 2; ++nt) {
      bf16x8 bfr = *(const bf16x8*)(Vt + (nt * 16 + l15) * 140 + ks * 32 + lhi * 8);
      ofr[nt] = MFMA(pafr, bfr, ofr[nt]);
    }
  }
#pragma unroll
  for (int nt = 0; nt < 2; ++nt)
#pragma unroll
    for (int j = 0; j < 4; ++j) {
      int n = mb + lhi * 4 + j;
      if (n < NT) {
        int d = nt * 16 + l15;
        out[(size_t)(widx * NT + n) * 128 + head * 32 + d] = f2bf(ofr[nt][j]);
      }
    }
}

// ---------------- K45: proj + residual + LN2 + MLP (merged) ----------------
// Phase A: proj MFMA -> per-wave LDS bounce -> LN2 -> bf16 rows -> afr regs.
// Phase B: k5 MLP loop with afr in regs; pipelined GELU/fc2 halves.
// LDS = 52224 B (projT region reused) -> 3 blocks/CU.
__global__ __launch_bounds__(256, 2) void k45_proj_mlp(
    const unsigned short* __restrict__ ao, const unsigned short* __restrict__ projT,
    const float* __restrict__ proj_b, const float* __restrict__ x,
    const float* __restrict__ g2, const float* __restrict__ b2,
    const unsigned short* __restrict__ fc1T, const float* __restrict__ fc1_b,
    const unsigned short* __restrict__ fc2T, const float* __restrict__ fc2_b,
    float* __restrict__ out) {
  __shared__ __align__(16) char smem[52224];
  int tid = threadIdx.x, wv = tid >> 6, lane = tid & 63;
  int l15 = lane & 15, lhi = lane >> 4;
  int mbase = blockIdx.x * 128 + wv * 32;
  int rl = lane >> 2, c0 = (lane & 3) * 32;

  // ---------------- phase A: proj + residual + LN2 ----------------
  unsigned short* wsW = (unsigned short*)smem;             // [128][136]
#pragma unroll
  for (int u = 0; u < 8; ++u) {
    int flat = u * 2048 + tid * 8;
    *(bf16x8*)(&wsW[(flat >> 7) * 136 + (flat & 127)]) = *(const bf16x8*)(projT + flat);
  }
  bf16x8 aofr[2][4];
#pragma unroll
  for (int mt = 0; mt < 2; ++mt)
#pragma unroll
    for (int ks = 0; ks < 4; ++ks)
      aofr[mt][ks] = *(const bf16x8*)(ao + (size_t)(mbase + mt * 16 + l15) * 128 + ks * 32 + lhi * 8);
  __syncthreads();

  f32x4 acc[2][8] = {};
#pragma unroll
  for (int ks = 0; ks < 4; ++ks)
#pragma unroll
    for (int nt = 0; nt < 8; ++nt) {
      bf16x8 bfr = *(const bf16x8*)(&wsW[(nt * 16 + l15) * 136 + ks * 32 + lhi * 8]);
#pragma unroll
      for (int mt = 0; mt < 2; ++mt)
        acc[mt][nt] = MFMA(aofr[mt][ks], bfr, acc[mt][nt]);
    }
  __syncthreads();   // wsW reads done -> reuse as per-wave bounce (8704 B/wave)

  float* bounce = (float*)(smem + wv * 8704);              // [16][136] fp32
  unsigned short* zt = (unsigned short*)(smem + wv * 8704); // [16][136] bf16
  float pb[8];
#pragma unroll
  for (int nt = 0; nt < 8; ++nt) pb[nt] = proj_b[nt * 16 + l15];

  bf16x8 afr[2][4];
  size_t srows[2];
#pragma unroll
  for (int mt = 0; mt < 2; ++mt) {
#pragma unroll
    for (int nt = 0; nt < 8; ++nt)
#pragma unroll
      for (int j = 0; j < 4; ++j)
        bounce[(lhi * 4 + j) * 136 + nt * 16 + l15] = acc[mt][nt][j] + pb[nt];
    WAVE_LDS_FENCE();

    int t = mbase + mt * 16 + rl;
    size_t srow = srow_of(t);
    srows[mt] = srow;
    const float* xr = x + srow * 128 + c0;
    float vals[32];
    float s = 0.f, ss = 0.f;
#pragma unroll
    for (int i = 0; i < 8; ++i) {
      float4 pv = *(const float4*)(bounce + rl * 136 + c0 + 4 * i);
      float4 xv = *(const float4*)(xr + 4 * i);
      float a0 = pv.x + xv.x, a1 = pv.y + xv.y, a2 = pv.z + xv.z, a3 = pv.w + xv.w;
      vals[4 * i] = a0; vals[4 * i + 1] = a1; vals[4 * i + 2] = a2; vals[4 * i + 3] = a3;
      s += a0 + a1 + a2 + a3;
      ss += a0 * a0 + a1 * a1 + a2 * a2 + a3 * a3;
    }
    s += __shfl_xor(s, 1);  ss += __shfl_xor(ss, 1);
    s += __shfl_xor(s, 2);  ss += __shfl_xor(ss, 2);
    float mu = s * (1.f / 128.f);
    float var = ss * (1.f / 128.f) - mu * mu;
    float inv = __builtin_amdgcn_rsqf(var + 1e-5f);
    unsigned pk[16];
#pragma unroll
    for (int i = 0; i < 8; ++i) {
      float4 g = *(const float4*)(g2 + c0 + 4 * i);
      float4 b = *(const float4*)(b2 + c0 + 4 * i);
      pk[2 * i]     = f2bf2((vals[4 * i]     - mu) * inv * g.x + b.x,
                            (vals[4 * i + 1] - mu) * inv * g.y + b.y);
      pk[2 * i + 1] = f2bf2((vals[4 * i + 2] - mu) * inv * g.z + b.z,
                            (vals[4 * i + 3] - mu) * inv * g.w + b.w);
    }
    WAVE_LDS_FENCE();   // fp32 reads done before bf16 alias overwrite
#pragma unroll
    for (int i = 0; i < 16; ++i)
      *(unsigned*)(zt + rl * 136 + c0 + 2 * i) = pk[i];
    WAVE_LDS_FENCE();   // zt writes done before afr reads
#pragma unroll
    for (int ks = 0; ks < 4; ++ks)
      afr[mt][ks] = *(const bf16x8*)(zt + l15 * 136 + ks * 32 + lhi * 8);
    WAVE_LDS_FENCE();   // afr reads done before next mt overwrites region
  }

  // prefetch first MLP weight chunk while waiting at the phase barrier
  bf16x8 pfA[4], pfB[4];
#pragma unroll
  for (int u = 0; u < 4; ++u) pfA[u] = *(const bf16x8*)(fc1T + u * 2048 + tid * 8);
#pragma unroll
  for (int u = 0; u < 4; ++u) {
    int flat = u * 2048 + tid * 8;
    pfB[u] = *(const bf16x8*)(fc2T + (size_t)(flat >> 6) * 512 + (flat & 63));
  }
  __syncthreads();   // phase A regions dead -> phase B layout

  // ---------------- phase B: MLP ----------------
  unsigned short* wsA = (unsigned short*)smem;             // [64][132]
  unsigned short* wsB = wsA + 64 * 132;                    // [128][68]
  unsigned short* hw  = wsB + 128 * 68 + wv * (32 * 70);   // per-wave [32][70]

  f32x4 oacc[2][8] = {};
  for (int ch = 0; ch < 8; ++ch) {
#pragma unroll
    for (int u = 0; u < 4; ++u) {
      int flat = u * 2048 + tid * 8;
      *(bf16x8*)(&wsA[(flat >> 7) * 132 + (flat & 127)]) = pfA[u];
      *(bf16x8*)(&wsB[(flat >> 6) * 68 + (flat & 63)]) = pfB[u];
    }
    __syncthreads();
    if (ch < 7) {
#pragma unroll
      for (int u = 0; u < 4; ++u)
        pfA[u] = *(const bf16x8*)(fc1T + (ch + 1) * 8192 + u * 2048 + tid * 8);
#pragma unroll
      for (int u = 0; u < 4; ++u) {
        int flat = u * 2048 + tid * 8;
        pfB[u] = *(const bf16x8*)(fc2T + (size_t)(flat >> 6) * 512 + (ch + 1) * 64 + (flat & 63));
      }
    }
    // fc1: h[32 x 64] per wave
    f32x4 hacc[2][4] = {};
#pragma unroll
    for (int ks = 0; ks < 4; ++ks)
#pragma unroll
      for (int nt = 0; nt < 4; ++nt) {
        bf16x8 bfr = *(const bf16x8*)(&wsA[(nt * 16 + l15) * 132 + ks * 32 + lhi * 8]);
#pragma unroll
        for (int mt = 0; mt < 2; ++mt)
          hacc[mt][nt] = MFMA(afr[mt][ks], bfr, hacc[mt][nt]);
      }
    // pipelined halves: GELU/write(k 0..31) -> fc2 ks=0 -> GELU/write(k 32..63) -> fc2 ks=1
#pragma unroll
    for (int half = 0; half < 2; ++half) {
#pragma unroll
      for (int mt = 0; mt < 2; ++mt)
#pragma unroll
        for (int nt2 = 0; nt2 < 2; ++nt2) {
          int nt = half * 2 + nt2;
#pragma unroll
          for (int j = 0; j < 4; ++j) {
            int r = mt * 16 + lhi * 4 + j;
            int hcol = ch * 64 + nt * 16 + l15;
            float hv = hacc[mt][nt][j] + fc1_b[hcol];
            float targ = hv * (1.5957691216f + 0.0713548162f * hv * hv);
            float gv = hv * __builtin_amdgcn_rcpf(1.0f + __expf(-targ));
            hw[r * 70 + nt * 16 + l15] = f2bf(gv);
          }
        }
      bf16x8 a2[2];
#pragma unroll
      for (int mt = 0; mt < 2; ++mt)
        a2[mt] = *(const bf16x8*)(&hw[(mt * 16 + l15) * 70 + half * 32 + lhi * 8]);
#pragma unroll
      for (int nt = 0; nt < 8; ++nt) {
        bf16x8 bfr = *(const bf16x8*)(&wsB[(nt * 16 + l15) * 68 + half * 32 + lhi * 8]);
#pragma unroll
        for (int mt = 0; mt < 2; ++mt)
          oacc[mt][nt] = MFMA(a2[mt], bfr, oacc[mt][nt]);
      }
    }
    __syncthreads();
  }

  // ---------------- epilogue: out via fp32 bounce, float4 stores ----------
  float* ob = (float*)(smem + wv * 8704);                  // [16][136] fp32
  float fb[8];
#pragma unroll
  for (int nt = 0; nt < 8; ++nt) fb[nt] = fc2_b[nt * 16 + l15];
#pragma unroll
  for (int mt = 0; mt < 2; ++mt) {
#pragma unroll
    for (int nt = 0; nt < 8; ++nt)
#pragma unroll
      for (int j = 0; j < 4; ++j)
        ob[(lhi * 4 + j) * 136 + nt * 16 + l15] = oacc[mt][nt][j] + fb[nt];
    WAVE_LDS_FENCE();
    float* orow = out + srows[mt] * 128 + c0;
#pragma unroll
    for (int i = 0; i < 8; ++i)
      *(float4*)(orow + 4 * i) = *(const float4*)(ob + rl * 136 + c0 + 4 * i);
    WAVE_LDS_FENCE();
  }
}

// ---------------------------------------------------------------------------
extern "C" void kernel_launch(void* const* d_in, const int* in_sizes, int n_in,
                              void* d_out, int out_size, void* d_ws, size_t ws_size,
                              hipStream_t stream) {
  const float* x      = (const float*)d_in[0];
  const float* mask   = (const float*)d_in[1];
  const int*   rel    = (const int*)d_in[2];
  const float* n1g    = (const float*)d_in[3];
  const float* n1b    = (const float*)d_in[4];
  const float* qkv_w  = (const float*)d_in[5];
  const float* qkv_b  = (const float*)d_in[6];
  const float* rpb    = (const float*)d_in[7];
  const float* proj_w = (const float*)d_in[8];
  const float* proj_b = (const float*)d_in[9];
  const float* n2g    = (const float*)d_in[10];
  const float* n2b    = (const float*)d_in[11];
  const float* fc1_w  = (const float*)d_in[12];
  const float* fc1_b  = (const float*)d_in[13];
  const float* fc2_w  = (const float*)d_in[14];
  const float* fc2_b  = (const float*)d_in[15];
  float* out = (float*)d_out;

  char* ws = (char*)d_ws;
  const size_t SZ = (size_t)NTOK * 128 * 2;
  unsigned short* win   = (unsigned short*)(ws);          // ao scratch
  unsigned short* qb    = (unsigned short*)(ws + SZ);
  unsigned short* kb    = (unsigned short*)(ws + 2 * SZ);
  unsigned short* vb    = (unsigned short*)(ws + 3 * SZ);
  unsigned short* qkvT  = (unsigned short*)(ws + 4 * SZ);
  unsigned short* projT = qkvT + 384 * 128;
  unsigned short* fc1T  = projT + 128 * 128;
  unsigned short* fc2T  = fc1T + 512 * 128;
  unsigned short* cmb   = fc2T + 128 * 512;     // 4*8*9604 bf16 = 614 KB
  float* qbb            = (float*)(cmb + (size_t)4 * 8 * NN);
  unsigned short* ao = win;

  k0_prep<<<256, 256, 0, stream>>>(qkv_w, proj_w, fc1_w, fc2_w, n1g, n1b, qkv_b,
                                   qkvT, projT, fc1T, fc2T, qbb);
  k0b_cmb<<<(4 * 8 * NN + 255) / 256, 256, 0, stream>>>(rel, rpb, mask, cmb);
  k2_qkv<<<NTOK / 128, 256, 0, stream>>>(x, qkvT, qbb, qb, kb, vb);
  k3_attn<<<NWIN * 4, 512, 0, stream>>>(qb, kb, vb, cmb, ao);
  k45_proj_mlp<<<NTOK / 128, 256, 0, stream>>>(ao, projT, proj_b, x, n2g, n2b,
                                               fc1T, fc1_b, fc2T, fc2_b, out);
}

// Round 11
// 352.849 us; speedup vs baseline: 1.3574x; 1.3574x over previous
//
#include <hip/hip_runtime.h>
#include <hip/hip_bf16.h>

typedef __attribute__((ext_vector_type(8))) short bf16x8;
typedef __attribute__((ext_vector_type(4))) float f32x4;

#define MFMA(a,b,c) __builtin_amdgcn_mfma_f32_16x16x32_bf16((a),(b),(c),0,0,0)
#define WAVE_LDS_FENCE() do { asm volatile("s_waitcnt lgkmcnt(0)" ::: "memory"); \
                              __builtin_amdgcn_sched_barrier(0); } while (0)

static constexpr int NTOK = 8 * 8 * 56 * 56;   // 200704 tokens
static constexpr int NT   = 98;                // tokens per window
static constexpr int NWIN = 2048;              // total windows
static constexpr int NN   = NT * NT;           // 9604

__device__ __forceinline__ unsigned short f2bf(float f) {
  unsigned r;
  asm("v_cvt_pk_bf16_f32 %0, %1, %1" : "=v"(r) : "v"(f));
  return (unsigned short)r;
}
__device__ __forceinline__ unsigned f2bf2(float lo, float hi) {
  unsigned r;
  asm("v_cvt_pk_bf16_f32 %0, %1, %2" : "=v"(r) : "v"(lo), "v"(hi));
  return r;
}
__device__ __forceinline__ float bf2f(unsigned short s) {
  union { unsigned u; float f; } v; v.u = ((unsigned)s) << 16; return v.f;
}
union U8 { unsigned u[4]; bf16x8 v; };

// map window-token t -> spatial row index (shifted partition)
__device__ __forceinline__ size_t srow_of(int t) {
  int widx = t / NT, n = t - widx * NT;
  int bb = widx >> 8, wb = widx & 255;
  int dW = wb >> 6, hW = (wb >> 3) & 7, wW = wb & 7;
  int dr = n / 49, rem = n - dr * 49, hr = rem / 7, wr = rem - hr * 7;
  int dsh = (dW * 2 + dr + 1) & 7;
  int hs = hW * 7 + hr + 3; if (hs >= 56) hs -= 56;
  int wsv = wW * 7 + wr + 3; if (wsv >= 56) wsv -= 56;
  return ((size_t)(bb * 8 + dsh) * 56 + hs) * 56 + wsv;
}

// ---------------- K0: weight transpose + bf16 cast + LN1/scale fold --------
__global__ __launch_bounds__(256) void k0_prep(
    const float* __restrict__ qkv_w, const float* __restrict__ proj_w,
    const float* __restrict__ fc1_w, const float* __restrict__ fc2_w,
    const float* __restrict__ n1g, const float* __restrict__ n1b,
    const float* __restrict__ qkv_b,
    unsigned short* __restrict__ qkvT, unsigned short* __restrict__ projT,
    unsigned short* __restrict__ fc1T, unsigned short* __restrict__ fc2T,
    float* __restrict__ qbb) {
  int idx = blockIdx.x * 256 + threadIdx.x;
  if (idx < 384 * 128) {
    int n = idx >> 7, k = idx & 127;
    float sc = n < 128 ? 0.17677669529663687f : 1.0f;
    qkvT[idx] = f2bf(qkv_w[k * 384 + n] * n1g[k] * sc);
  }
  if (idx < 128 * 128) { int n = idx >> 7, k = idx & 127; projT[idx] = f2bf(proj_w[k * 128 + n]); }
  if (idx < 512 * 128) { int n = idx >> 7, k = idx & 127; fc1T[idx] = f2bf(fc1_w[k * 512 + n]); }
  if (idx < 128 * 512) { int n = idx >> 9, k = idx & 511; fc2T[idx] = f2bf(fc2_w[k * 128 + n]); }
  if (idx < 384) {
    float acc = qkv_b[idx];
    for (int k = 0; k < 128; ++k) acc += n1b[k] * qkv_w[k * 384 + idx];
    qbb[idx] = acc * (idx < 128 ? 0.17677669529663687f : 1.0f);
  }
}

// ---------------- K0b: bias+mask table, vector-load layout -----------------
// cmb2[(hc*98 + i)*128 + l15*8 + nt] = bias(i, col=nt*16+l15), 0 if col>=98/nt==7
__global__ __launch_bounds__(256) void k0b_cmb(
    const int* __restrict__ rel, const float* __restrict__ rpb,
    const float* __restrict__ mask, unsigned short* __restrict__ cmb) {
  int idx = blockIdx.x * 256 + threadIdx.x;
  if (idx >= 4 * 8 * 98 * 128) return;
  int nt = idx & 7;
  int l15 = (idx >> 3) & 15;
  int rest = idx >> 7;               // hc*98 + i
  int i = rest % 98;
  int hc = rest / 98;
  int h = hc >> 3, cls = hc & 7;
  int col = nt * 16 + l15;
  float val = 0.f;
  if (nt < 7 && col < 98) {
    int wb_rep = ((cls >> 2) & 1 ? 192 : 0) + ((cls >> 1) & 1 ? 56 : 0) + ((cls & 1) ? 7 : 0);
    val = rpb[rel[i * NT + col] * 4 + h] + mask[(size_t)wb_rep * NN + i * NT + col];
  }
  cmb[idx] = f2bf(val);
}

// ---------------- K2: fused LN1 + shift/partition + QKV GEMM ---------------
__global__ __launch_bounds__(256, 2) void k2_qkv(
    const float* __restrict__ x, const unsigned short* __restrict__ qkvT,
    const float* __restrict__ qbb,
    unsigned short* __restrict__ q, unsigned short* __restrict__ k,
    unsigned short* __restrict__ v) {
  __shared__ __align__(16) unsigned short wsW[64 * 136];   // 17408 B
  int tid = threadIdx.x, wv = tid >> 6, lane = tid & 63;
  int l15 = lane & 15, lhi = lane >> 4;
  int mbase = blockIdx.x * 128 + wv * 32;

  bf16x8 afr[2][4];
#pragma unroll
  for (int mt = 0; mt < 2; ++mt) {
    int row = mbase + mt * 16 + l15;
    size_t srow = srow_of(row);
    const float* xr = x + srow * 128 + lhi * 8;
    float xv[4][8];
    float s = 0.f, ss = 0.f;
#pragma unroll
    for (int ks = 0; ks < 4; ++ks) {
      float4 lo = *(const float4*)(xr + ks * 32);
      float4 hi = *(const float4*)(xr + ks * 32 + 4);
      xv[ks][0] = lo.x; xv[ks][1] = lo.y; xv[ks][2] = lo.z; xv[ks][3] = lo.w;
      xv[ks][4] = hi.x; xv[ks][5] = hi.y; xv[ks][6] = hi.z; xv[ks][7] = hi.w;
#pragma unroll
      for (int e = 0; e < 8; ++e) { s += xv[ks][e]; ss += xv[ks][e] * xv[ks][e]; }
    }
    s += __shfl_xor(s, 16);  ss += __shfl_xor(ss, 16);
    s += __shfl_xor(s, 32);  ss += __shfl_xor(ss, 32);
    float mu = s * (1.f / 128.f);
    float var = ss * (1.f / 128.f) - mu * mu;
    float inv = __builtin_amdgcn_rsqf(var + 1e-5f);
#pragma unroll
    for (int ks = 0; ks < 4; ++ks) {
      U8 t;
#pragma unroll
      for (int p = 0; p < 4; ++p)
        t.u[p] = f2bf2((xv[ks][2 * p] - mu) * inv, (xv[ks][2 * p + 1] - mu) * inv);
      afr[mt][ks] = t.v;
    }
  }

  int rbase[2][4];
#pragma unroll
  for (int mt = 0; mt < 2; ++mt)
#pragma unroll
    for (int j = 0; j < 4; ++j) {
      int r = mbase + mt * 16 + lhi * 4 + j;
      int widx = r / NT, n = r - widx * NT;
      rbase[mt][j] = widx * 392 + n;
    }

  bf16x8 pf[4];
#pragma unroll
  for (int u = 0; u < 4; ++u) pf[u] = *(const bf16x8*)(qkvT + u * 2048 + tid * 8);

  for (int ch = 0; ch < 6; ++ch) {
#pragma unroll
    for (int u = 0; u < 4; ++u) {
      int flat = u * 2048 + tid * 8;
      *(bf16x8*)(&wsW[(flat >> 7) * 136 + (flat & 127)]) = pf[u];
    }
    __syncthreads();
    if (ch < 5) {
#pragma unroll
      for (int u = 0; u < 4; ++u)
        pf[u] = *(const bf16x8*)(qkvT + (ch + 1) * 8192 + u * 2048 + tid * 8);
    }
    f32x4 acc[2][4] = {};
#pragma unroll
    for (int ks = 0; ks < 4; ++ks)
#pragma unroll
      for (int nt = 0; nt < 4; ++nt) {
        bf16x8 bfr = *(const bf16x8*)(&wsW[(nt * 16 + l15) * 136 + ks * 32 + lhi * 8]);
#pragma unroll
        for (int mt = 0; mt < 2; ++mt)
          acc[mt][nt] = MFMA(afr[mt][ks], bfr, acc[mt][nt]);
      }
#pragma unroll
    for (int nt = 0; nt < 4; ++nt) {
      int col = ch * 64 + nt * 16 + l15;
      int which = col >> 7, head = (col >> 5) & 3, hd = col & 31;
      unsigned short* outb = which == 0 ? q : (which == 1 ? k : v);
      float bias = qbb[col];
#pragma unroll
      for (int mt = 0; mt < 2; ++mt)
#pragma unroll
        for (int j = 0; j < 4; ++j) {
          float val = acc[mt][nt][j] + bias;
          outb[(size_t)(rbase[mt][j] + head * 98) * 32 + hd] = f2bf(val);
        }
    }
    __syncthreads();
  }
}

// ---------------- K3: window attention, 512 thr, one 16-row tile per wave --
__global__ __launch_bounds__(512) void k3_attn(
    const unsigned short* __restrict__ q, const unsigned short* __restrict__ kk,
    const unsigned short* __restrict__ vv, const unsigned short* __restrict__ cmb,
    unsigned short* __restrict__ out) {
  __shared__ __align__(16) unsigned short Vt[32 * 140];    // 8960 B
  __shared__ __align__(16) unsigned short Pw[7][16 * 140]; // 31360 B
  int bid = blockIdx.x;
  int widx = bid >> 2, head = bid & 3;
  int wb = widx & 255;
  size_t base = (size_t)(widx * 4 + head) * NT * 32;
  int tid = threadIdx.x, wv = tid >> 6, lane = tid & 63;
  int l15 = lane & 15, lhi = lane >> 4;

  for (int idx = tid; idx < NT * 32; idx += 512) {
    int j = idx >> 5, d = idx & 31;
    Vt[d * 140 + j] = vv[base + idx];
  }
  for (int idx = tid; idx < 32 * 30; idx += 512) {
    int d = idx / 30, j = 98 + idx % 30;
    Vt[d * 140 + j] = 0;
  }
  __syncthreads();
  if (wv >= 7) return;           // no barriers after this point

  int cls = (((wb >> 6) == 3) << 2) | ((((wb >> 3) & 7) == 7) << 1) | ((int)((wb & 7) == 7));
  const unsigned short* cw = cmb + (size_t)(head * 8 + cls) * 98 * 128;
  unsigned short* P = Pw[wv];
  int mb = wv * 16;

  bf16x8 afr = *(const bf16x8*)(q + base + (size_t)(mb + l15) * 32 + lhi * 8);
  f32x4 sfr[7];
#pragma unroll
  for (int nt = 0; nt < 7; ++nt) {
    bf16x8 bfr = *(const bf16x8*)(kk + base + (size_t)(nt * 16 + l15) * 32 + lhi * 8);
    f32x4 zz = {};
    sfr[nt] = MFMA(afr, bfr, zz);
  }
#pragma unroll
  for (int j = 0; j < 4; ++j) {
    int i = mb + lhi * 4 + j;
    int ic = i < 97 ? i : 97;
    // one 16B load fetches this row's 7 bias values for this lane's columns
    bf16x8 cv = *(const bf16x8*)(cw + ic * 128 + l15 * 8);
    float sv[7];
#pragma unroll
    for (int nt = 0; nt < 7; ++nt) {
      int colc = nt * 16 + l15;
      float s = fminf(fmaxf(sfr[nt][j], -1e4f), 1e4f);
      float bm = bf2f((unsigned short)cv[nt]);
      sv[nt] = (i < NT && colc < NT) ? (s + bm) : -1e30f;
    }
    float mx = sv[0];
#pragma unroll
    for (int nt = 1; nt < 7; ++nt) mx = fmaxf(mx, sv[nt]);
#pragma unroll
    for (int m2 = 1; m2 < 16; m2 <<= 1) mx = fmaxf(mx, __shfl_xor(mx, m2));
    float sum = 0.f, p[7];
#pragma unroll
    for (int nt = 0; nt < 7; ++nt) { p[nt] = __expf(sv[nt] - mx); sum += p[nt]; }
#pragma unroll
    for (int m2 = 1; m2 < 16; m2 <<= 1) sum += __shfl_xor(sum, m2);
    float inv = __builtin_amdgcn_rcpf(sum);
    int iloc = lhi * 4 + j;
#pragma unroll
    for (int nt = 0; nt < 7; ++nt)
      P[iloc * 140 + nt * 16 + l15] = f2bf(p[nt] * inv);
    P[iloc * 140 + 112 + l15] = 0;
  }
  WAVE_LDS_FENCE();

  f32x4 ofr[2] = {};
#pragma unroll
  for (int ks = 0; ks < 4; ++ks) {
    bf16x8 pafr = *(const bf16x8*)(P + l15 * 140 + ks * 32 + lhi * 8);
#pragma unroll
    for (int nt = 0; nt < 2; ++nt) {
      bf16x8 bfr = *(const bf16x8*)(Vt + (nt * 16 + l15) * 140 + ks * 32 + lhi * 8);
      ofr[nt] = MFMA(pafr, bfr, ofr[nt]);
    }
  }
#pragma unroll
  for (int nt = 0; nt < 2; ++nt)
#pragma unroll
    for (int j = 0; j < 4; ++j) {
      int n = mb + lhi * 4 + j;
      if (n < NT) {
        int d = nt * 16 + l15;
        out[(size_t)(widx * NT + n) * 128 + head * 32 + d] = f2bf(ofr[nt][j]);
      }
    }
}

// ---------------- K4: proj + reverse/unshift + residual + LN2 --------------
// x rows prefetched early (T14); epilogue via LDS bounce, vector stores
__global__ __launch_bounds__(256, 3) void k4_proj_ln(
    const unsigned short* __restrict__ ao, const unsigned short* __restrict__ projT,
    const float* __restrict__ proj_b, const float* __restrict__ x,
    const float* __restrict__ g2, const float* __restrict__ b2,
    unsigned short* __restrict__ z) {
  __shared__ __align__(16) unsigned short wsW[128 * 136];   // 34816 B
  int tid = threadIdx.x, wv = tid >> 6, lane = tid & 63;
  int l15 = lane & 15, lhi = lane >> 4;
  int mbase = blockIdx.x * 128 + wv * 32;
  int rl = lane >> 2, c0 = (lane & 3) * 32;

  size_t srows[2];
  srows[0] = srow_of(mbase + rl);
  srows[1] = srow_of(mbase + 16 + rl);
  // T14: issue mt=0's residual loads NOW, consume after the MFMA phase
  float4 x0[8];
#pragma unroll
  for (int i = 0; i < 8; ++i)
    x0[i] = *(const float4*)(x + srows[0] * 128 + c0 + 4 * i);

#pragma unroll
  for (int u = 0; u < 8; ++u) {
    int flat = u * 2048 + tid * 8;
    *(bf16x8*)(&wsW[(flat >> 7) * 136 + (flat & 127)]) = *(const bf16x8*)(projT + flat);
  }
  bf16x8 afr[2][4];
#pragma unroll
  for (int mt = 0; mt < 2; ++mt)
#pragma unroll
    for (int ks = 0; ks < 4; ++ks)
      afr[mt][ks] = *(const bf16x8*)(ao + (size_t)(mbase + mt * 16 + l15) * 128 + ks * 32 + lhi * 8);
  __syncthreads();

  f32x4 acc[2][8] = {};
#pragma unroll
  for (int ks = 0; ks < 4; ++ks)
#pragma unroll
    for (int nt = 0; nt < 8; ++nt) {
      bf16x8 bfr = *(const bf16x8*)(&wsW[(nt * 16 + l15) * 136 + ks * 32 + lhi * 8]);
#pragma unroll
      for (int mt = 0; mt < 2; ++mt)
        acc[mt][nt] = MFMA(afr[mt][ks], bfr, acc[mt][nt]);
    }
  __syncthreads();   // all waves done reading wsW -> reuse as fp32 bounce

  // issue mt=1's residual loads before processing mt=0
  float4 x1[8];
#pragma unroll
  for (int i = 0; i < 8; ++i)
    x1[i] = *(const float4*)(x + srows[1] * 128 + c0 + 4 * i);

  float* bounce = (float*)wsW + wv * (16 * 132);  // 16x132 fp32 per wave
  float pb[8];
#pragma unroll
  for (int nt = 0; nt < 8; ++nt) pb[nt] = proj_b[nt * 16 + l15];

#pragma unroll
  for (int mt = 0; mt < 2; ++mt) {
#pragma unroll
    for (int nt = 0; nt < 8; ++nt)
#pragma unroll
      for (int j = 0; j < 4; ++j)
        bounce[(lhi * 4 + j) * 132 + nt * 16 + l15] = acc[mt][nt][j] + pb[nt];
    WAVE_LDS_FENCE();

    size_t srow = srows[mt];
    float vals[32];
    float s = 0.f, ss = 0.f;
#pragma unroll
    for (int i = 0; i < 8; ++i) {
      float4 pv = *(const float4*)(bounce + rl * 132 + c0 + 4 * i);
      float4 xv = mt == 0 ? x0[i] : x1[i];
      float a0 = pv.x + xv.x, a1 = pv.y + xv.y, a2 = pv.z + xv.z, a3 = pv.w + xv.w;
      vals[4 * i] = a0; vals[4 * i + 1] = a1; vals[4 * i + 2] = a2; vals[4 * i + 3] = a3;
      s += a0 + a1 + a2 + a3;
      ss += a0 * a0 + a1 * a1 + a2 * a2 + a3 * a3;
    }
    s += __shfl_xor(s, 1);  ss += __shfl_xor(ss, 1);
    s += __shfl_xor(s, 2);  ss += __shfl_xor(ss, 2);
    float mu = s * (1.f / 128.f);
    float var = ss * (1.f / 128.f) - mu * mu;
    float inv = __builtin_amdgcn_rsqf(var + 1e-5f);
    unsigned pk[16];
#pragma unroll
    for (int i = 0; i < 8; ++i) {
      float4 g = *(const float4*)(g2 + c0 + 4 * i);
      float4 b = *(const float4*)(b2 + c0 + 4 * i);
      pk[2 * i]     = f2bf2((vals[4 * i]     - mu) * inv * g.x + b.x,
                            (vals[4 * i + 1] - mu) * inv * g.y + b.y);
      pk[2 * i + 1] = f2bf2((vals[4 * i + 2] - mu) * inv * g.z + b.z,
                            (vals[4 * i + 3] - mu) * inv * g.w + b.w);
    }
    unsigned* zp = (unsigned*)(z + srow * 128 + c0);
#pragma unroll
    for (int i = 0; i < 4; ++i)
      *(uint4*)(zp + 4 * i) = make_uint4(pk[4 * i], pk[4 * i + 1], pk[4 * i + 2], pk[4 * i + 3]);
    WAVE_LDS_FENCE();
  }
}

// ---------------- K5: MLP fc1 + GELU + fc2, 256 thr, 3 blocks/CU -----------
__global__ __launch_bounds__(256, 2) void k5_mlp(
    const unsigned short* __restrict__ z, const unsigned short* __restrict__ fc1T,
    const float* __restrict__ fc1_b, const unsigned short* __restrict__ fc2T,
    const float* __restrict__ fc2_b, float* __restrict__ out) {
  __shared__ __align__(16) unsigned short wsA[64 * 132];   // 16896 B
  __shared__ __align__(16) unsigned short wsB[128 * 68];   // 17408 B
  __shared__ __align__(16) unsigned short hl[4][32 * 70];  // 17920 B
  int tid = threadIdx.x, wv = tid >> 6, lane = tid & 63;
  int l15 = lane & 15, lhi = lane >> 4;
  int mbase = blockIdx.x * 128 + wv * 32;
  unsigned short* hw = hl[wv];

  bf16x8 afr[2][4];
#pragma unroll
  for (int mt = 0; mt < 2; ++mt)
#pragma unroll
    for (int ks = 0; ks < 4; ++ks)
      afr[mt][ks] = *(const bf16x8*)(z + (size_t)(mbase + mt * 16 + l15) * 128 + ks * 32 + lhi * 8);

  bf16x8 pfA[4], pfB[4];
#pragma unroll
  for (int u = 0; u < 4; ++u) pfA[u] = *(const bf16x8*)(fc1T + u * 2048 + tid * 8);
#pragma unroll
  for (int u = 0; u < 4; ++u) {
    int flat = u * 2048 + tid * 8;
    pfB[u] = *(const bf16x8*)(fc2T + (size_t)(flat >> 6) * 512 + (flat & 63));
  }

  f32x4 oacc[2][8] = {};
  for (int ch = 0; ch < 8; ++ch) {
#pragma unroll
    for (int u = 0; u < 4; ++u) {
      int flat = u * 2048 + tid * 8;
      *(bf16x8*)(&wsA[(flat >> 7) * 132 + (flat & 127)]) = pfA[u];
      *(bf16x8*)(&wsB[(flat >> 6) * 68 + (flat & 63)]) = pfB[u];
    }
    __syncthreads();
    if (ch < 7) {
#pragma unroll
      for (int u = 0; u < 4; ++u)
        pfA[u] = *(const bf16x8*)(fc1T + (ch + 1) * 8192 + u * 2048 + tid * 8);
#pragma unroll
      for (int u = 0; u < 4; ++u) {
        int flat = u * 2048 + tid * 8;
        pfB[u] = *(const bf16x8*)(fc2T + (size_t)(flat >> 6) * 512 + (ch + 1) * 64 + (flat & 63));
      }
    }
    f32x4 hacc[2][4] = {};
#pragma unroll
    for (int ks = 0; ks < 4; ++ks)
#pragma unroll
      for (int nt = 0; nt < 4; ++nt) {
        bf16x8 bfr = *(const bf16x8*)(&wsA[(nt * 16 + l15) * 132 + ks * 32 + lhi * 8]);
#pragma unroll
        for (int mt = 0; mt < 2; ++mt)
          hacc[mt][nt] = MFMA(afr[mt][ks], bfr, hacc[mt][nt]);
      }
#pragma unroll
    for (int mt = 0; mt < 2; ++mt)
#pragma unroll
      for (int nt = 0; nt < 4; ++nt)
#pragma unroll
        for (int j = 0; j < 4; ++j) {
          int r = mt * 16 + lhi * 4 + j;
          int hcol = ch * 64 + nt * 16 + l15;
          float hv = hacc[mt][nt][j] + fc1_b[hcol];
          float targ = hv * (1.5957691216f + 0.0713548162f * hv * hv);
          float gv = hv * __builtin_amdgcn_rcpf(1.0f + __expf(-targ));
          hw[r * 70 + nt * 16 + l15] = f2bf(gv);
        }
    WAVE_LDS_FENCE();
#pragma unroll
    for (int ks = 0; ks < 2; ++ks) {
      bf16x8 a2[2];
#pragma unroll
      for (int mt = 0; mt < 2; ++mt)
        a2[mt] = *(const bf16x8*)(&hw[(mt * 16 + l15) * 70 + ks * 32 + lhi * 8]);
#pragma unroll
      for (int nt = 0; nt < 8; ++nt) {
        bf16x8 bfr = *(const bf16x8*)(&wsB[(nt * 16 + l15) * 68 + ks * 32 + lhi * 8]);
#pragma unroll
        for (int mt = 0; mt < 2; ++mt)
          oacc[mt][nt] = MFMA(a2[mt], bfr, oacc[mt][nt]);
      }
    }
    WAVE_LDS_FENCE();
    __syncthreads();
  }
#pragma unroll
  for (int mt = 0; mt < 2; ++mt)
#pragma unroll
    for (int nt = 0; nt < 8; ++nt)
#pragma unroll
      for (int j = 0; j < 4; ++j) {
        int r = mbase + mt * 16 + lhi * 4 + j;
        out[(size_t)r * 128 + nt * 16 + l15] = oacc[mt][nt][j] + fc2_b[nt * 16 + l15];
      }
}

// ---------------------------------------------------------------------------
extern "C" void kernel_launch(void* const* d_in, const int* in_sizes, int n_in,
                              void* d_out, int out_size, void* d_ws, size_t ws_size,
                              hipStream_t stream) {
  const float* x      = (const float*)d_in[0];
  const float* mask   = (const float*)d_in[1];
  const int*   rel    = (const int*)d_in[2];
  const float* n1g    = (const float*)d_in[3];
  const float* n1b    = (const float*)d_in[4];
  const float* qkv_w  = (const float*)d_in[5];
  const float* qkv_b  = (const float*)d_in[6];
  const float* rpb    = (const float*)d_in[7];
  const float* proj_w = (const float*)d_in[8];
  const float* proj_b = (const float*)d_in[9];
  const float* n2g    = (const float*)d_in[10];
  const float* n2b    = (const float*)d_in[11];
  const float* fc1_w  = (const float*)d_in[12];
  const float* fc1_b  = (const float*)d_in[13];
  const float* fc2_w  = (const float*)d_in[14];
  const float* fc2_b  = (const float*)d_in[15];
  float* out = (float*)d_out;

  char* ws = (char*)d_ws;
  const size_t SZ = (size_t)NTOK * 128 * 2;
  unsigned short* win   = (unsigned short*)(ws);          // ao scratch
  unsigned short* qb    = (unsigned short*)(ws + SZ);
  unsigned short* kb    = (unsigned short*)(ws + 2 * SZ);
  unsigned short* vb    = (unsigned short*)(ws + 3 * SZ);
  unsigned short* qkvT  = (unsigned short*)(ws + 4 * SZ);
  unsigned short* projT = qkvT + 384 * 128;
  unsigned short* fc1T  = projT + 128 * 128;
  unsigned short* fc2T  = fc1T + 512 * 128;
  unsigned short* cmb   = fc2T + 128 * 512;     // 4*8*98*128 bf16 = 784 KB
  float* qbb            = (float*)(cmb + (size_t)4 * 8 * 98 * 128);
  unsigned short* ao = win;
  unsigned short* zb = qb;

  k0_prep<<<256, 256, 0, stream>>>(qkv_w, proj_w, fc1_w, fc2_w, n1g, n1b, qkv_b,
                                   qkvT, projT, fc1T, fc2T, qbb);
  k0b_cmb<<<(4 * 8 * 98 * 128 + 255) / 256, 256, 0, stream>>>(rel, rpb, mask, cmb);
  k2_qkv<<<NTOK / 128, 256, 0, stream>>>(x, qkvT, qbb, qb, kb, vb);
  k3_attn<<<NWIN * 4, 512, 0, stream>>>(qb, kb, vb, cmb, ao);
  k4_proj_ln<<<NTOK / 128, 256, 0, stream>>>(ao, projT, proj_b, x, n2g, n2b, zb);
  k5_mlp<<<NTOK / 128, 256, 0, stream>>>(zb, fc1T, fc1_b, fc2T, fc2_b, out);
}